// Round 1
// baseline (1267.393 us; speedup 1.0000x reference)
//
#include <hip/hip_runtime.h>
#include <hip/hip_bf16.h>

// Problem constants
#define BATCH 32
#define LQ 64
#define LD 512
#define EMB 300
#define FFH 100
#define ATTD 32
#define NH 8
#define NK 21

__device__ __forceinline__ float wave_sum(float v) {
    #pragma unroll
    for (int off = 32; off > 0; off >>= 1) v += __shfl_xor(v, off);
    return v;
}
__device__ __forceinline__ float wave_max(float v) {
    #pragma unroll
    for (int off = 32; off > 0; off >>= 1) v = fmaxf(v, __shfl_xor(v, off));
    return v;
}

// ---------------- elementwise: x = emb * mask(token) ----------------
__global__ void maskmul_kernel(const float* __restrict__ emb, const float* __restrict__ mask,
                               float* __restrict__ out, int n) {
    int i = blockIdx.x * blockDim.x + threadIdx.x;
    if (i < n) out[i] = emb[i] * mask[i / EMB];
}

// ---------------- generic tiled GEMM: C[M,N] = A[M,K] @ B[K,N] + bias (+relu / +residual) ----
// EPI: 0 = bias, 1 = bias+relu, 2 = bias+residual
template <int EPI>
__global__ __launch_bounds__(256) void gemm_nn(const float* __restrict__ A, const float* __restrict__ Bw,
                                               const float* __restrict__ bias, const float* __restrict__ R,
                                               float* __restrict__ C, int M, int N, int K) {
    __shared__ __align__(16) float As[16][68];   // [k][m], padded to avoid bank conflicts on store
    __shared__ __align__(16) float Bs[16][64];   // [k][n]
    const int tid = threadIdx.x;
    const int m0 = blockIdx.y * 64, n0 = blockIdx.x * 64;
    const int tr = tid >> 4, tc = tid & 15;
    float acc[4][4] = {};

    for (int k0 = 0; k0 < K; k0 += 16) {
        #pragma unroll
        for (int i = 0; i < 4; i++) {
            int idx = tid + i * 256;
            int r = idx >> 4, cl = idx & 15;
            int kk = k0 + cl;
            As[cl][r] = (kk < K) ? A[(size_t)(m0 + r) * K + kk] : 0.f;
        }
        #pragma unroll
        for (int i = 0; i < 4; i++) {
            int idx = tid + i * 256;
            int r = idx >> 6, cl = idx & 63;
            int kk = k0 + r;
            int n = n0 + cl;
            Bs[r][cl] = (kk < K && n < N) ? Bw[(size_t)kk * N + n] : 0.f;
        }
        __syncthreads();
        #pragma unroll
        for (int kk = 0; kk < 16; kk++) {
            float4 a4 = *(const float4*)&As[kk][tr * 4];
            float4 b4 = *(const float4*)&Bs[kk][tc * 4];
            float av[4] = {a4.x, a4.y, a4.z, a4.w};
            float bv[4] = {b4.x, b4.y, b4.z, b4.w};
            #pragma unroll
            for (int i = 0; i < 4; i++)
                #pragma unroll
                for (int j = 0; j < 4; j++) acc[i][j] += av[i] * bv[j];
        }
        __syncthreads();
    }
    #pragma unroll
    for (int i = 0; i < 4; i++) {
        int row = m0 + tr * 4 + i;
        #pragma unroll
        for (int j = 0; j < 4; j++) {
            int col = n0 + tc * 4 + j;
            if (col < N) {
                float v = acc[i][j] + bias[col];
                if (EPI == 1) v = fmaxf(v, 0.f);
                if (EPI == 2) v += R[(size_t)row * N + col];
                C[(size_t)row * N + col] = v;
            }
        }
    }
}

// ---------------- LayerNorm (ddof=1, eps added to std), one wave per token (300 elems) ------
__global__ __launch_bounds__(256) void ln_kernel(const float* __restrict__ X, const float* __restrict__ g,
                                                 const float* __restrict__ bta, float* __restrict__ Y, int M) {
    int wid = (blockIdx.x * 256 + threadIdx.x) >> 6;
    int lane = threadIdx.x & 63;
    if (wid >= M) return;
    const float* x = X + (size_t)wid * EMB;
    float v[5];
    float s = 0.f;
    #pragma unroll
    for (int r = 0; r < 5; r++) {
        int idx = lane + r * 64;
        float val = (idx < EMB) ? x[idx] : 0.f;
        v[r] = val;
        s += val;
    }
    s = wave_sum(s);
    float mean = s * (1.f / EMB);
    float s2 = 0.f;
    #pragma unroll
    for (int r = 0; r < 5; r++) {
        int idx = lane + r * 64;
        if (idx < EMB) { float d = v[r] - mean; s2 += d * d; }
    }
    s2 = wave_sum(s2);
    float stdv = sqrtf(s2 * (1.f / (EMB - 1)));
    float inv = 1.f / (stdv + 1e-6f);
    float* y = Y + (size_t)wid * EMB;
    #pragma unroll
    for (int r = 0; r < 5; r++) {
        int idx = lane + r * 64;
        if (idx < EMB) y[idx] = g[idx] * (v[r] - mean) * inv + bta[idx];
    }
}

// ---------------- attention: one wave per (b, head, q-row). head dim = 4. ----------------
// c layout: [B*T, 96]  (q | k | v, each 32 = 8 heads * 4)
template <int NR>  // NR = T/64
__global__ __launch_bounds__(256) void attn_kernel(const float* __restrict__ c, const float* __restrict__ mask,
                                                   float* __restrict__ o32) {
    const int T = NR * 64;
    int wid = (blockIdx.x * 256 + threadIdx.x) >> 6;
    int lane = threadIdx.x & 63;
    int b = wid / (NH * T);
    int rem = wid % (NH * T);
    int h = rem / T;
    int qi = rem % T;
    const float* base = c + (size_t)b * T * 96;
    float4 qv = *(const float4*)(base + (size_t)qi * 96 + h * 4);
    const float inv_scale = 1.0f / sqrtf(37.0f);  // sqrt(EMB // NH)

    float sc[NR], mk[NR];
    float mx = -3.4e38f;
    #pragma unroll
    for (int r = 0; r < NR; r++) {
        int j = r * 64 + lane;
        float4 kv = *(const float4*)(base + (size_t)j * 96 + 32 + h * 4);
        float m = mask[b * T + j];
        float s = (qv.x * kv.x + qv.y * kv.y + qv.z * kv.z + qv.w * kv.w) * inv_scale * m;
        sc[r] = s;
        mk[r] = m;
        mx = fmaxf(mx, s);
    }
    mx = wave_max(mx);
    float Sall = 0.f, Sm = 0.f, ox = 0.f, oy = 0.f, oz = 0.f, ow = 0.f;
    #pragma unroll
    for (int r = 0; r < NR; r++) {
        int j = r * 64 + lane;
        float e = expf(sc[r] - mx);
        Sall += e;
        float em = e * mk[r];
        Sm += em;
        float4 vv = *(const float4*)(base + (size_t)j * 96 + 64 + h * 4);
        ox += em * vv.x; oy += em * vv.y; oz += em * vv.z; ow += em * vv.w;
    }
    Sall = wave_sum(Sall);
    Sm = wave_sum(Sm);
    ox = wave_sum(ox); oy = wave_sum(oy); oz = wave_sum(oz); ow = wave_sum(ow);
    if (lane == 0) {
        float inv = 1.f / (Sm + 1e-13f * Sall);
        float4 o = {ox * inv, oy * inv, oz * inv, ow * inv};
        *(float4*)(o32 + (size_t)(b * T + qi) * ATTD + h * 4) = o;
    }
}

// ---------------- mix + L2 normalize: one wave per token ----------------
__global__ __launch_bounds__(256) void mixnorm_kernel(const float* __restrict__ x, const float* __restrict__ xc,
                                                      const float* __restrict__ mask, const float* __restrict__ mixer,
                                                      float* __restrict__ out) {
    int wid = (blockIdx.x * 256 + threadIdx.x) >> 6;
    int lane = threadIdx.x & 63;
    float mixv = mixer[0];
    float mval = mask[wid];
    const float* xr = x + (size_t)wid * EMB;
    const float* xcr = xc + (size_t)wid * EMB;
    float v[5];
    float s2 = 0.f;
    #pragma unroll
    for (int r = 0; r < 5; r++) {
        int idx = lane + r * 64;
        float val = 0.f;
        if (idx < EMB) val = (mixv * xr[idx] + (1.f - mixv) * xcr[idx]) * mval;
        v[r] = val;
        s2 += val * val;
    }
    s2 = wave_sum(s2);
    float inv = 1.f / (sqrtf(s2) + 1e-13f);
    float* o = out + (size_t)wid * EMB;
    #pragma unroll
    for (int r = 0; r < 5; r++) {
        int idx = lane + r * 64;
        if (idx < EMB) o[idx] = v[r] * inv;
    }
}

// ---------------- batched NT GEMM: cos[b] = qn[b] (64x300) @ dn[b]^T (300x512) ----------------
__global__ __launch_bounds__(256) void gemm_nt_cos(const float* __restrict__ Qn, const float* __restrict__ Dn,
                                                   float* __restrict__ Cos) {
    int b = blockIdx.y;
    int n0 = blockIdx.x * 64;
    const float* A = Qn + (size_t)b * LQ * EMB;
    const float* Bm = Dn + (size_t)b * LD * EMB;
    __shared__ __align__(16) float As[16][68];
    __shared__ __align__(16) float Bs[16][68];
    const int tid = threadIdx.x;
    const int tr = tid >> 4, tc = tid & 15;
    float acc[4][4] = {};
    for (int k0 = 0; k0 < EMB; k0 += 16) {
        #pragma unroll
        for (int i = 0; i < 4; i++) {
            int idx = tid + i * 256;
            int r = idx >> 4, cl = idx & 15;
            int kk = k0 + cl;
            As[cl][r] = (kk < EMB) ? A[(size_t)r * EMB + kk] : 0.f;
            Bs[cl][r] = (kk < EMB) ? Bm[(size_t)(n0 + r) * EMB + kk] : 0.f;
        }
        __syncthreads();
        #pragma unroll
        for (int kk = 0; kk < 16; kk++) {
            float4 a4 = *(const float4*)&As[kk][tr * 4];
            float4 b4 = *(const float4*)&Bs[kk][tc * 4];
            float av[4] = {a4.x, a4.y, a4.z, a4.w};
            float bv[4] = {b4.x, b4.y, b4.z, b4.w};
            #pragma unroll
            for (int i = 0; i < 4; i++)
                #pragma unroll
                for (int j = 0; j < 4; j++) acc[i][j] += av[i] * bv[j];
        }
        __syncthreads();
    }
    #pragma unroll
    for (int i = 0; i < 4; i++) {
        int row = tr * 4 + i;
        #pragma unroll
        for (int j = 0; j < 4; j++) {
            int col = n0 + tc * 4 + j;
            Cos[(size_t)b * LQ * LD + (size_t)row * LD + col] = acc[i][j];
        }
    }
}

// ---------------- kernel pooling: one wave per (b, qi); 21 RBF kernels ----------------
__global__ __launch_bounds__(256) void pool_kernel(const float* __restrict__ Cos, const float* __restrict__ mask_q,
                                                   const float* __restrict__ mask_d, const float* __restrict__ nn_scaler,
                                                   float* __restrict__ lp) {
    int wid = (blockIdx.x * 256 + threadIdx.x) >> 6;
    int lane = threadIdx.x & 63;
    int b = wid >> 6, qi = wid & 63;
    const float* crow = Cos + ((size_t)b * LQ + qi) * LD;
    const float* md = mask_d + b * LD;
    float acc[NK];
    #pragma unroll
    for (int k = 0; k < NK; k++) acc[k] = 0.f;
    #pragma unroll
    for (int r = 0; r < LD / 64; r++) {
        int dj = r * 64 + lane;
        float m = md[dj];
        if (m != 0.f) {
            float cv = crow[dj];
            #pragma unroll
            for (int k = 0; k < NK; k++) {
                float mu = (k == 0) ? 1.0f : (0.95f - 0.1f * (k - 1));
                float neg_inv = (k == 0) ? -500000.0f : -50.0f;  // -1/(2*sigma^2)
                float d = cv - mu;
                acc[k] += expf(d * d * neg_inv);
            }
        }
    }
    float mq = mask_q[b * LQ + qi];
    float ns = nn_scaler[0];
    #pragma unroll
    for (int k = 0; k < NK; k++) {
        float s = wave_sum(acc[k]);
        if (lane == 0) lp[((size_t)b * LQ + qi) * NK + k] = log2f(fmaxf(s, 1e-10f)) * ns * mq;
    }
}

// ---------------- final: out[b] = sum_k dense_w[k] * sum_qi lp[b,qi,k] ----------------
__global__ void final_kernel(const float* __restrict__ lp, const float* __restrict__ dense_w,
                             float* __restrict__ out) {
    int b = blockIdx.x;
    int t = threadIdx.x;  // 64 threads
    float s = 0.f;
    if (t < NK) {
        for (int qi = 0; qi < LQ; qi++) s += lp[((size_t)b * LQ + qi) * NK + t];
        s *= dense_w[t];
    }
    s = wave_sum(s);
    if (t == 0) out[b] = s;
}

// ---------------- host-side encoder driver ----------------
static void run_encoder(const float* x_in, float* x_out, int T, const float* mask,
                        const float* ff_w1, const float* ff_b1, const float* ff_w2, const float* ff_b2,
                        const float* ln1_g, const float* ln1_b, const float* att_w, const float* att_b,
                        const float* out_w, const float* out_b, const float* ln2_g, const float* ln2_b,
                        float* t1, float* t2, float* hb, float* cb, float* o32, hipStream_t stream) {
    int M = BATCH * T;
    const float* xcur = x_in;
    for (int l = 0; l < 2; l++) {
        gemm_nn<1><<<dim3(2, M / 64), 256, 0, stream>>>(xcur, ff_w1 + l * EMB * FFH, ff_b1 + l * FFH,
                                                        nullptr, t1, M, FFH, EMB);
        gemm_nn<2><<<dim3(5, M / 64), 256, 0, stream>>>(t1, ff_w2 + l * FFH * EMB, ff_b2 + l * EMB,
                                                        xcur, t2, M, EMB, FFH);
        ln_kernel<<<M / 4, 256, 0, stream>>>(t2, ln1_g + l * EMB, ln1_b + l * EMB, hb, M);
        gemm_nn<0><<<dim3(2, M / 64), 256, 0, stream>>>(hb, att_w + l * EMB * 96, att_b + l * 96,
                                                        nullptr, cb, M, 96, EMB);
        if (T == LD)
            attn_kernel<8><<<(BATCH * NH * LD) / 4, 256, 0, stream>>>(cb, mask, o32);
        else
            attn_kernel<1><<<(BATCH * NH * LQ) / 4, 256, 0, stream>>>(cb, mask, o32);
        gemm_nn<2><<<dim3(5, M / 64), 256, 0, stream>>>(o32, out_w + l * ATTD * EMB, out_b + l * EMB,
                                                        hb, t2, M, EMB, ATTD);
        ln_kernel<<<M / 4, 256, 0, stream>>>(t2, ln2_g + l * EMB, ln2_b + l * EMB, x_out, M);
        xcur = x_out;
    }
}

extern "C" void kernel_launch(void* const* d_in, const int* in_sizes, int n_in,
                              void* d_out, int out_size, void* d_ws, size_t ws_size,
                              hipStream_t stream) {
    (void)in_sizes; (void)n_in; (void)out_size; (void)ws_size;
    const float* q_embed  = (const float*)d_in[0];
    const float* d_embed  = (const float*)d_in[1];
    const float* mask_q   = (const float*)d_in[2];
    const float* mask_d   = (const float*)d_in[3];
    const float* mixer    = (const float*)d_in[4];
    const float* nn_scaler= (const float*)d_in[5];
    const float* ff_w1    = (const float*)d_in[6];
    const float* ff_b1    = (const float*)d_in[7];
    const float* ff_w2    = (const float*)d_in[8];
    const float* ff_b2    = (const float*)d_in[9];
    const float* ln1_g    = (const float*)d_in[10];
    const float* ln1_b    = (const float*)d_in[11];
    const float* att_w    = (const float*)d_in[12];
    const float* att_b    = (const float*)d_in[13];
    const float* out_w    = (const float*)d_in[14];
    const float* out_b    = (const float*)d_in[15];
    const float* ln2_g    = (const float*)d_in[16];
    const float* ln2_b    = (const float*)d_in[17];
    const float* dense_w  = (const float*)d_in[18];
    float* out = (float*)d_out;

    // workspace layout (floats)
    float* ws = (float*)d_ws;
    float* xq  = ws;                       // 32*64*300   = 614400
    float* xd  = xq + 614400;              // 32*512*300  = 4915200
    float* qc  = xd + 4915200;             // 614400
    float* dc  = qc + 614400;              // 4915200
    float* t1  = dc + 4915200;             // 32*512*100  = 1638400
    float* t2  = t1 + 1638400;             // 4915200
    float* hb  = t2 + 4915200;             // 4915200
    float* cb  = hb + 4915200;             // 32*512*96   = 1572864
    float* o32 = cb + 1572864;             // 32*512*32   = 524288
    // reused after encoders complete:
    float* qn   = t1;                      // 614400
    float* dn   = hb;                      // 4915200
    float* cosb = t2;                      // 32*64*512   = 1048576
    float* lp   = o32;                     // 32*64*21    = 43008

    // 1. masked inputs
    maskmul_kernel<<<(614400 + 255) / 256, 256, 0, stream>>>(q_embed, mask_q, xq, 614400);
    maskmul_kernel<<<(4915200 + 255) / 256, 256, 0, stream>>>(d_embed, mask_d, xd, 4915200);

    // 2. encoders
    run_encoder(xq, qc, LQ, mask_q, ff_w1, ff_b1, ff_w2, ff_b2, ln1_g, ln1_b,
                att_w, att_b, out_w, out_b, ln2_g, ln2_b, t1, t2, hb, cb, o32, stream);
    run_encoder(xd, dc, LD, mask_d, ff_w1, ff_b1, ff_w2, ff_b2, ln1_g, ln1_b,
                att_w, att_b, out_w, out_b, ln2_g, ln2_b, t1, t2, hb, cb, o32, stream);

    // 3. mix + normalize
    mixnorm_kernel<<<(BATCH * LQ) / 4, 256, 0, stream>>>(xq, qc, mask_q, mixer, qn);
    mixnorm_kernel<<<(BATCH * LD) / 4, 256, 0, stream>>>(xd, dc, mask_d, mixer, dn);

    // 4. cosine matrix
    gemm_nt_cos<<<dim3(LD / 64, BATCH), 256, 0, stream>>>(qn, dn, cosb);

    // 5. kernel pooling
    pool_kernel<<<(BATCH * LQ) / 4, 256, 0, stream>>>(cosb, mask_q, mask_d, nn_scaler, lp);

    // 6. final projection
    final_kernel<<<BATCH, 64, 0, stream>>>(lp, dense_w, out);
}

// Round 2
// 888.912 us; speedup vs baseline: 1.4258x; 1.4258x over previous
//
#include <hip/hip_runtime.h>
#include <hip/hip_bf16.h>

// Problem constants
#define BATCH 32
#define LQ 64
#define LD 512
#define EMB 300
#define FFH 100
#define ATTD 32
#define NH 8
#define NK 21

__device__ __forceinline__ float wave_sum(float v) {
    #pragma unroll
    for (int off = 32; off > 0; off >>= 1) v += __shfl_xor(v, off);
    return v;
}

// ---------------- elementwise: x = emb * mask(token) ----------------
__global__ void maskmul_kernel(const float* __restrict__ emb, const float* __restrict__ mask,
                               float* __restrict__ out, int n) {
    int i = blockIdx.x * blockDim.x + threadIdx.x;
    if (i < n) out[i] = emb[i] * mask[i / EMB];
}

// ---------------- generic tiled GEMM: C[M,N] = A[M,K] @ B[K,N] + bias (+relu / +residual) ----
// EPI: 0 = bias, 1 = bias+relu, 2 = bias+residual
template <int EPI>
__global__ __launch_bounds__(256) void gemm_nn(const float* __restrict__ A, const float* __restrict__ Bw,
                                               const float* __restrict__ bias, const float* __restrict__ R,
                                               float* __restrict__ C, int M, int N, int K) {
    __shared__ __align__(16) float As[16][68];   // [k][m], padded to avoid bank conflicts on store
    __shared__ __align__(16) float Bs[16][64];   // [k][n]
    const int tid = threadIdx.x;
    const int m0 = blockIdx.y * 64, n0 = blockIdx.x * 64;
    const int tr = tid >> 4, tc = tid & 15;
    float acc[4][4] = {};

    for (int k0 = 0; k0 < K; k0 += 16) {
        #pragma unroll
        for (int i = 0; i < 4; i++) {
            int idx = tid + i * 256;
            int r = idx >> 4, cl = idx & 15;
            int kk = k0 + cl;
            As[cl][r] = (kk < K) ? A[(size_t)(m0 + r) * K + kk] : 0.f;
        }
        #pragma unroll
        for (int i = 0; i < 4; i++) {
            int idx = tid + i * 256;
            int r = idx >> 6, cl = idx & 63;
            int kk = k0 + r;
            int n = n0 + cl;
            Bs[r][cl] = (kk < K && n < N) ? Bw[(size_t)kk * N + n] : 0.f;
        }
        __syncthreads();
        #pragma unroll
        for (int kk = 0; kk < 16; kk++) {
            float4 a4 = *(const float4*)&As[kk][tr * 4];
            float4 b4 = *(const float4*)&Bs[kk][tc * 4];
            float av[4] = {a4.x, a4.y, a4.z, a4.w};
            float bv[4] = {b4.x, b4.y, b4.z, b4.w};
            #pragma unroll
            for (int i = 0; i < 4; i++)
                #pragma unroll
                for (int j = 0; j < 4; j++) acc[i][j] += av[i] * bv[j];
        }
        __syncthreads();
    }
    #pragma unroll
    for (int i = 0; i < 4; i++) {
        int row = m0 + tr * 4 + i;
        #pragma unroll
        for (int j = 0; j < 4; j++) {
            int col = n0 + tc * 4 + j;
            if (col < N) {
                float v = acc[i][j] + bias[col];
                if (EPI == 1) v = fmaxf(v, 0.f);
                if (EPI == 2) v += R[(size_t)row * N + col];
                C[(size_t)row * N + col] = v;
            }
        }
    }
}

// ---------------- LayerNorm (ddof=1, eps added to std), one wave per token (300 elems) ------
__global__ __launch_bounds__(256) void ln_kernel(const float* __restrict__ X, const float* __restrict__ g,
                                                 const float* __restrict__ bta, float* __restrict__ Y, int M) {
    int wid = (blockIdx.x * 256 + threadIdx.x) >> 6;
    int lane = threadIdx.x & 63;
    if (wid >= M) return;
    const float* x = X + (size_t)wid * EMB;
    float v[5];
    float s = 0.f;
    #pragma unroll
    for (int r = 0; r < 5; r++) {
        int idx = lane + r * 64;
        float val = (idx < EMB) ? x[idx] : 0.f;
        v[r] = val;
        s += val;
    }
    s = wave_sum(s);
    float mean = s * (1.f / EMB);
    float s2 = 0.f;
    #pragma unroll
    for (int r = 0; r < 5; r++) {
        int idx = lane + r * 64;
        if (idx < EMB) { float d = v[r] - mean; s2 += d * d; }
    }
    s2 = wave_sum(s2);
    float stdv = sqrtf(s2 * (1.f / (EMB - 1)));
    float inv = 1.f / (stdv + 1e-6f);
    float* y = Y + (size_t)wid * EMB;
    #pragma unroll
    for (int r = 0; r < 5; r++) {
        int idx = lane + r * 64;
        if (idx < EMB) y[idx] = g[idx] * (v[r] - mean) * inv + bta[idx];
    }
}

// ---------------- attention: one block per (b, head); K/V/mask staged in LDS ----------------
// c layout: [B*T, 96]  (q | k | v, each 32 = 8 heads * 4)
// Each thread owns q-rows r = tid, tid+512, ...; the k-loop reads LDS via wave-wide
// broadcast (all lanes same address -> conflict-free, deduped).
template <int T>
__global__ __launch_bounds__(512) void attn_block_kernel(const float* __restrict__ c,
                                                         const float* __restrict__ mask,
                                                         float* __restrict__ o32) {
    __shared__ float Ks[T * 4];
    __shared__ float Vs[T * 4];
    __shared__ float Ms[T];
    const int b = blockIdx.x / NH;
    const int h = blockIdx.x % NH;
    const float* base = c + (size_t)b * T * 96;
    const int tid = threadIdx.x;

    for (int idx = tid; idx < T * 4; idx += 512) {
        int j = idx >> 2, e = idx & 3;
        Ks[idx] = base[(size_t)j * 96 + ATTD + h * 4 + e];
        Vs[idx] = base[(size_t)j * 96 + 2 * ATTD + h * 4 + e];
    }
    for (int idx = tid; idx < T; idx += 512) Ms[idx] = mask[b * T + idx];
    __syncthreads();

    const float inv_scale = 0.16439898730535729f;  // 1/sqrt(37) = 1/sqrt(EMB // NH)
    for (int r = tid; r < T; r += 512) {
        float4 qv = *(const float4*)(base + (size_t)r * 96 + h * 4);
        float mx = -3.4e38f;
        #pragma unroll 4
        for (int k = 0; k < T; k++) {
            float4 kv = *(const float4*)&Ks[k * 4];
            float s = (qv.x * kv.x + qv.y * kv.y + qv.z * kv.z + qv.w * kv.w) * inv_scale * Ms[k];
            mx = fmaxf(mx, s);
        }
        float Sall = 0.f, Sm = 0.f, ox = 0.f, oy = 0.f, oz = 0.f, ow = 0.f;
        #pragma unroll 4
        for (int k = 0; k < T; k++) {
            float4 kv = *(const float4*)&Ks[k * 4];
            float s = (qv.x * kv.x + qv.y * kv.y + qv.z * kv.z + qv.w * kv.w) * inv_scale * Ms[k];
            float e = expf(s - mx);
            Sall += e;
            float em = e * Ms[k];
            Sm += em;
            float4 vv = *(const float4*)&Vs[k * 4];
            ox += em * vv.x; oy += em * vv.y; oz += em * vv.z; ow += em * vv.w;
        }
        float inv = 1.f / (Sm + 1e-13f * Sall);
        float4 o = {ox * inv, oy * inv, oz * inv, ow * inv};
        *(float4*)(o32 + (size_t)(b * T + r) * ATTD + h * 4) = o;
    }
}

// ---------------- mix + L2 normalize: one wave per token ----------------
__global__ __launch_bounds__(256) void mixnorm_kernel(const float* __restrict__ x, const float* __restrict__ xc,
                                                      const float* __restrict__ mask, const float* __restrict__ mixer,
                                                      float* __restrict__ out) {
    int wid = (blockIdx.x * 256 + threadIdx.x) >> 6;
    int lane = threadIdx.x & 63;
    float mixv = mixer[0];
    float mval = mask[wid];
    const float* xr = x + (size_t)wid * EMB;
    const float* xcr = xc + (size_t)wid * EMB;
    float v[5];
    float s2 = 0.f;
    #pragma unroll
    for (int r = 0; r < 5; r++) {
        int idx = lane + r * 64;
        float val = 0.f;
        if (idx < EMB) val = (mixv * xr[idx] + (1.f - mixv) * xcr[idx]) * mval;
        v[r] = val;
        s2 += val * val;
    }
    s2 = wave_sum(s2);
    float inv = 1.f / (sqrtf(s2) + 1e-13f);
    float* o = out + (size_t)wid * EMB;
    #pragma unroll
    for (int r = 0; r < 5; r++) {
        int idx = lane + r * 64;
        if (idx < EMB) o[idx] = v[r] * inv;
    }
}

// ---------------- batched NT GEMM: cos[b] = qn[b] (64x300) @ dn[b]^T (300x512) ----------------
__global__ __launch_bounds__(256) void gemm_nt_cos(const float* __restrict__ Qn, const float* __restrict__ Dn,
                                                   float* __restrict__ Cos) {
    int b = blockIdx.y;
    int n0 = blockIdx.x * 64;
    const float* A = Qn + (size_t)b * LQ * EMB;
    const float* Bm = Dn + (size_t)b * LD * EMB;
    __shared__ __align__(16) float As[16][68];
    __shared__ __align__(16) float Bs[16][68];
    const int tid = threadIdx.x;
    const int tr = tid >> 4, tc = tid & 15;
    float acc[4][4] = {};
    for (int k0 = 0; k0 < EMB; k0 += 16) {
        #pragma unroll
        for (int i = 0; i < 4; i++) {
            int idx = tid + i * 256;
            int r = idx >> 4, cl = idx & 15;
            int kk = k0 + cl;
            As[cl][r] = (kk < EMB) ? A[(size_t)r * EMB + kk] : 0.f;
            Bs[cl][r] = (kk < EMB) ? Bm[(size_t)(n0 + r) * EMB + kk] : 0.f;
        }
        __syncthreads();
        #pragma unroll
        for (int kk = 0; kk < 16; kk++) {
            float4 a4 = *(const float4*)&As[kk][tr * 4];
            float4 b4 = *(const float4*)&Bs[kk][tc * 4];
            float av[4] = {a4.x, a4.y, a4.z, a4.w};
            float bv[4] = {b4.x, b4.y, b4.z, b4.w};
            #pragma unroll
            for (int i = 0; i < 4; i++)
                #pragma unroll
                for (int j = 0; j < 4; j++) acc[i][j] += av[i] * bv[j];
        }
        __syncthreads();
    }
    #pragma unroll
    for (int i = 0; i < 4; i++) {
        int row = tr * 4 + i;
        #pragma unroll
        for (int j = 0; j < 4; j++) {
            int col = n0 + tc * 4 + j;
            Cos[(size_t)b * LQ * LD + (size_t)row * LD + col] = acc[i][j];
        }
    }
}

// ---------------- kernel pooling: one wave per (b, qi); 21 RBF kernels ----------------
__global__ __launch_bounds__(256) void pool_kernel(const float* __restrict__ Cos, const float* __restrict__ mask_q,
                                                   const float* __restrict__ mask_d, const float* __restrict__ nn_scaler,
                                                   float* __restrict__ lp) {
    int wid = (blockIdx.x * 256 + threadIdx.x) >> 6;
    int lane = threadIdx.x & 63;
    int b = wid >> 6, qi = wid & 63;
    const float* crow = Cos + ((size_t)b * LQ + qi) * LD;
    const float* md = mask_d + b * LD;
    float acc[NK];
    #pragma unroll
    for (int k = 0; k < NK; k++) acc[k] = 0.f;
    #pragma unroll
    for (int r = 0; r < LD / 64; r++) {
        int dj = r * 64 + lane;
        float m = md[dj];
        if (m != 0.f) {
            float cv = crow[dj];
            #pragma unroll
            for (int k = 0; k < NK; k++) {
                float mu = (k == 0) ? 1.0f : (0.95f - 0.1f * (k - 1));
                float neg_inv = (k == 0) ? -500000.0f : -50.0f;  // -1/(2*sigma^2)
                float d = cv - mu;
                acc[k] += expf(d * d * neg_inv);
            }
        }
    }
    float mq = mask_q[b * LQ + qi];
    float ns = nn_scaler[0];
    #pragma unroll
    for (int k = 0; k < NK; k++) {
        float s = wave_sum(acc[k]);
        if (lane == 0) lp[((size_t)b * LQ + qi) * NK + k] = log2f(fmaxf(s, 1e-10f)) * ns * mq;
    }
}

// ---------------- final: out[b] = sum_k dense_w[k] * sum_qi lp[b,qi,k] ----------------
__global__ void final_kernel(const float* __restrict__ lp, const float* __restrict__ dense_w,
                             float* __restrict__ out) {
    int b = blockIdx.x;
    int t = threadIdx.x;  // 64 threads
    float s = 0.f;
    if (t < NK) {
        for (int qi = 0; qi < LQ; qi++) s += lp[((size_t)b * LQ + qi) * NK + t];
        s *= dense_w[t];
    }
    s = wave_sum(s);
    if (t == 0) out[b] = s;
}

// ---------------- host-side encoder driver ----------------
static void run_encoder(const float* x_in, float* x_out, int T, const float* mask,
                        const float* ff_w1, const float* ff_b1, const float* ff_w2, const float* ff_b2,
                        const float* ln1_g, const float* ln1_b, const float* att_w, const float* att_b,
                        const float* out_w, const float* out_b, const float* ln2_g, const float* ln2_b,
                        float* t1, float* t2, float* hb, float* cb, float* o32, hipStream_t stream) {
    int M = BATCH * T;
    const float* xcur = x_in;
    for (int l = 0; l < 2; l++) {
        gemm_nn<1><<<dim3(2, M / 64), 256, 0, stream>>>(xcur, ff_w1 + l * EMB * FFH, ff_b1 + l * FFH,
                                                        nullptr, t1, M, FFH, EMB);
        gemm_nn<2><<<dim3(5, M / 64), 256, 0, stream>>>(t1, ff_w2 + l * FFH * EMB, ff_b2 + l * EMB,
                                                        xcur, t2, M, EMB, FFH);
        ln_kernel<<<M / 4, 256, 0, stream>>>(t2, ln1_g + l * EMB, ln1_b + l * EMB, hb, M);
        gemm_nn<0><<<dim3(2, M / 64), 256, 0, stream>>>(hb, att_w + l * EMB * 96, att_b + l * 96,
                                                        nullptr, cb, M, 96, EMB);
        if (T == LD)
            attn_block_kernel<LD><<<BATCH * NH, 512, 0, stream>>>(cb, mask, o32);
        else
            attn_block_kernel<LQ><<<BATCH * NH, 512, 0, stream>>>(cb, mask, o32);
        gemm_nn<2><<<dim3(5, M / 64), 256, 0, stream>>>(o32, out_w + l * ATTD * EMB, out_b + l * EMB,
                                                        hb, t2, M, EMB, ATTD);
        ln_kernel<<<M / 4, 256, 0, stream>>>(t2, ln2_g + l * EMB, ln2_b + l * EMB, x_out, M);
        xcur = x_out;
    }
}

extern "C" void kernel_launch(void* const* d_in, const int* in_sizes, int n_in,
                              void* d_out, int out_size, void* d_ws, size_t ws_size,
                              hipStream_t stream) {
    (void)in_sizes; (void)n_in; (void)out_size; (void)ws_size;
    const float* q_embed  = (const float*)d_in[0];
    const float* d_embed  = (const float*)d_in[1];
    const float* mask_q   = (const float*)d_in[2];
    const float* mask_d   = (const float*)d_in[3];
    const float* mixer    = (const float*)d_in[4];
    const float* nn_scaler= (const float*)d_in[5];
    const float* ff_w1    = (const float*)d_in[6];
    const float* ff_b1    = (const float*)d_in[7];
    const float* ff_w2    = (const float*)d_in[8];
    const float* ff_b2    = (const float*)d_in[9];
    const float* ln1_g    = (const float*)d_in[10];
    const float* ln1_b    = (const float*)d_in[11];
    const float* att_w    = (const float*)d_in[12];
    const float* att_b    = (const float*)d_in[13];
    const float* out_w    = (const float*)d_in[14];
    const float* out_b    = (const float*)d_in[15];
    const float* ln2_g    = (const float*)d_in[16];
    const float* ln2_b    = (const float*)d_in[17];
    const float* dense_w  = (const float*)d_in[18];
    float* out = (float*)d_out;

    // workspace layout (floats)
    float* ws = (float*)d_ws;
    float* xq  = ws;                       // 32*64*300   = 614400
    float* xd  = xq + 614400;              // 32*512*300  = 4915200
    float* qc  = xd + 4915200;             // 614400
    float* dc  = qc + 614400;              // 4915200
    float* t1  = dc + 4915200;             // 32*512*100  = 1638400
    float* t2  = t1 + 1638400;             // 4915200
    float* hb  = t2 + 4915200;             // 4915200
    float* cb  = hb + 4915200;             // 32*512*96   = 1572864
    float* o32 = cb + 1572864;             // 32*512*32   = 524288
    // reused after encoders complete:
    float* qn   = t1;                      // 614400
    float* dn   = hb;                      // 4915200
    float* cosb = t2;                      // 32*64*512   = 1048576
    float* lp   = o32;                     // 32*64*21    = 43008

    // 1. masked inputs
    maskmul_kernel<<<(614400 + 255) / 256, 256, 0, stream>>>(q_embed, mask_q, xq, 614400);
    maskmul_kernel<<<(4915200 + 255) / 256, 256, 0, stream>>>(d_embed, mask_d, xd, 4915200);

    // 2. encoders
    run_encoder(xq, qc, LQ, mask_q, ff_w1, ff_b1, ff_w2, ff_b2, ln1_g, ln1_b,
                att_w, att_b, out_w, out_b, ln2_g, ln2_b, t1, t2, hb, cb, o32, stream);
    run_encoder(xd, dc, LD, mask_d, ff_w1, ff_b1, ff_w2, ff_b2, ln1_g, ln1_b,
                att_w, att_b, out_w, out_b, ln2_g, ln2_b, t1, t2, hb, cb, o32, stream);

    // 3. mix + normalize
    mixnorm_kernel<<<(BATCH * LQ) / 4, 256, 0, stream>>>(xq, qc, mask_q, mixer, qn);
    mixnorm_kernel<<<(BATCH * LD) / 4, 256, 0, stream>>>(xd, dc, mask_d, mixer, dn);

    // 4. cosine matrix
    gemm_nt_cos<<<dim3(LD / 64, BATCH), 256, 0, stream>>>(qn, dn, cosb);

    // 5. kernel pooling
    pool_kernel<<<(BATCH * LQ) / 4, 256, 0, stream>>>(cosb, mask_q, mask_d, nn_scaler, lp);

    // 6. final projection
    final_kernel<<<BATCH, 64, 0, stream>>>(lp, dense_w, out);
}

// Round 3
// 735.634 us; speedup vs baseline: 1.7229x; 1.2084x over previous
//
#include <hip/hip_runtime.h>
#include <hip/hip_bf16.h>

// Problem constants
#define BATCH 32
#define LQ 64
#define LD 512
#define EMB 300
#define FFH 100
#define ATTD 32
#define NH 8
#define NK 21

__device__ __forceinline__ float wave_sum(float v) {
    #pragma unroll
    for (int off = 32; off > 0; off >>= 1) v += __shfl_xor(v, off);
    return v;
}

// ---------------- elementwise: x = emb * mask(token) ----------------
__global__ void maskmul_kernel(const float* __restrict__ emb, const float* __restrict__ mask,
                               float* __restrict__ out, int n) {
    int i = blockIdx.x * blockDim.x + threadIdx.x;
    if (i < n) out[i] = emb[i] * mask[i / EMB];
}

// ---------------- generic tiled GEMM: C[M,N] = A[M,K] @ B[K,N] + bias (+relu / +residual) ----
// EPI: 0 = bias, 1 = bias+relu, 2 = bias+residual
template <int EPI>
__global__ __launch_bounds__(256) void gemm_nn(const float* __restrict__ A, const float* __restrict__ Bw,
                                               const float* __restrict__ bias, const float* __restrict__ R,
                                               float* __restrict__ C, int M, int N, int K) {
    __shared__ __align__(16) float As[16][68];   // [k][m], padded to avoid bank conflicts on store
    __shared__ __align__(16) float Bs[16][64];   // [k][n]
    const int tid = threadIdx.x;
    const int m0 = blockIdx.y * 64, n0 = blockIdx.x * 64;
    const int tr = tid >> 4, tc = tid & 15;
    float acc[4][4] = {};

    for (int k0 = 0; k0 < K; k0 += 16) {
        #pragma unroll
        for (int i = 0; i < 4; i++) {
            int idx = tid + i * 256;
            int r = idx >> 4, cl = idx & 15;
            int kk = k0 + cl;
            As[cl][r] = (kk < K) ? A[(size_t)(m0 + r) * K + kk] : 0.f;
        }
        #pragma unroll
        for (int i = 0; i < 4; i++) {
            int idx = tid + i * 256;
            int r = idx >> 6, cl = idx & 63;
            int kk = k0 + r;
            int n = n0 + cl;
            Bs[r][cl] = (kk < K && n < N) ? Bw[(size_t)kk * N + n] : 0.f;
        }
        __syncthreads();
        #pragma unroll
        for (int kk = 0; kk < 16; kk++) {
            float4 a4 = *(const float4*)&As[kk][tr * 4];
            float4 b4 = *(const float4*)&Bs[kk][tc * 4];
            float av[4] = {a4.x, a4.y, a4.z, a4.w};
            float bv[4] = {b4.x, b4.y, b4.z, b4.w};
            #pragma unroll
            for (int i = 0; i < 4; i++)
                #pragma unroll
                for (int j = 0; j < 4; j++) acc[i][j] += av[i] * bv[j];
        }
        __syncthreads();
    }
    #pragma unroll
    for (int i = 0; i < 4; i++) {
        int row = m0 + tr * 4 + i;
        #pragma unroll
        for (int j = 0; j < 4; j++) {
            int col = n0 + tc * 4 + j;
            if (col < N) {
                float v = acc[i][j] + bias[col];
                if (EPI == 1) v = fmaxf(v, 0.f);
                if (EPI == 2) v += R[(size_t)row * N + col];
                C[(size_t)row * N + col] = v;
            }
        }
    }
}

// ---------------- LayerNorm (ddof=1, eps added to std), one wave per token (300 elems) ------
__global__ __launch_bounds__(256) void ln_kernel(const float* __restrict__ X, const float* __restrict__ g,
                                                 const float* __restrict__ bta, float* __restrict__ Y, int M) {
    int wid = (blockIdx.x * 256 + threadIdx.x) >> 6;
    int lane = threadIdx.x & 63;
    if (wid >= M) return;
    const float* x = X + (size_t)wid * EMB;
    float v[5];
    float s = 0.f;
    #pragma unroll
    for (int r = 0; r < 5; r++) {
        int idx = lane + r * 64;
        float val = (idx < EMB) ? x[idx] : 0.f;
        v[r] = val;
        s += val;
    }
    s = wave_sum(s);
    float mean = s * (1.f / EMB);
    float s2 = 0.f;
    #pragma unroll
    for (int r = 0; r < 5; r++) {
        int idx = lane + r * 64;
        if (idx < EMB) { float d = v[r] - mean; s2 += d * d; }
    }
    s2 = wave_sum(s2);
    float stdv = sqrtf(s2 * (1.f / (EMB - 1)));
    float inv = 1.f / (stdv + 1e-6f);
    float* y = Y + (size_t)wid * EMB;
    #pragma unroll
    for (int r = 0; r < 5; r++) {
        int idx = lane + r * 64;
        if (idx < EMB) y[idx] = g[idx] * (v[r] - mean) * inv + bta[idx];
    }
}

// ---------------- attention v3: single-pass (no max), premasked K/V in LDS, k-split ---------
// c layout: [B*T, 96]  (q | k | v, each 32 = 8 heads * 4)
// Block = RPB rows x KS k-slices (RPB*KS threads). Grid = B*NH*(T/RPB).
// Softmax without max-subtraction (shift-invariant; |s| is O(1) here).
// K,V rows premultiplied by mask at staging: masked k -> s=0 -> e=exp(0)=1 exactly,
// so Sm = Sall - nmask, and o accumulates e*(m*v) = 0 for masked k.
template <int T, int RPB, int KS>
__global__ __launch_bounds__(512) void attn_fused(const float* __restrict__ c,
                                                  const float* __restrict__ mask,
                                                  float* __restrict__ o32) {
    constexpr int BLK = RPB * KS;
    constexpr int NRB = T / RPB;
    __shared__ float4 Ks[T];
    __shared__ float4 Vs[T];
    __shared__ float part[RPB * 5 * (KS - 1)];
    __shared__ float nmask_s;
    const int bh = blockIdx.x / NRB;
    const int rb = blockIdx.x % NRB;
    const int b = bh / NH, h = bh % NH;
    const int tid = threadIdx.x;
    const float* base = c + (size_t)b * T * 96;

    if (tid == 0) nmask_s = 0.f;
    __syncthreads();
    float lnm = 0.f;
    for (int j = tid; j < T; j += BLK) {
        float m = mask[b * T + j];
        float4 kv = *(const float4*)(base + (size_t)j * 96 + ATTD + h * 4);
        float4 vv = *(const float4*)(base + (size_t)j * 96 + 2 * ATTD + h * 4);
        kv.x *= m; kv.y *= m; kv.z *= m; kv.w *= m;
        vv.x *= m; vv.y *= m; vv.z *= m; vv.w *= m;
        Ks[j] = kv;
        Vs[j] = vv;
        lnm += 1.f - m;
    }
    lnm = wave_sum(lnm);
    if ((tid & 63) == 0 && lnm != 0.f) atomicAdd(&nmask_s, lnm);
    __syncthreads();

    const int r = rb * RPB + (tid % RPB);
    const int ks = tid / RPB;   // uniform per wave (RPB is a multiple of 64)
    const float inv_scale = 0.16439898730535729f;  // 1/sqrt(37)
    float4 qv = *(const float4*)(base + (size_t)r * 96 + h * 4);
    qv.x *= inv_scale; qv.y *= inv_scale; qv.z *= inv_scale; qv.w *= inv_scale;

    float Sall = 0.f, ox = 0.f, oy = 0.f, oz = 0.f, ow = 0.f;
    constexpr int KC = T / KS;
    const int k0 = ks * KC;
    #pragma unroll 4
    for (int k = k0; k < k0 + KC; k++) {
        float4 kv = Ks[k];
        float4 vv = Vs[k];
        float s = fmaf(qv.x, kv.x, fmaf(qv.y, kv.y, fmaf(qv.z, kv.z, qv.w * kv.w)));
        float e = __expf(s);
        Sall += e;
        ox = fmaf(e, vv.x, ox);
        oy = fmaf(e, vv.y, oy);
        oz = fmaf(e, vv.z, oz);
        ow = fmaf(e, vv.w, ow);
    }
    if (ks > 0) {
        float* p = &part[((ks - 1) * RPB + (tid % RPB)) * 5];
        p[0] = Sall; p[1] = ox; p[2] = oy; p[3] = oz; p[4] = ow;
    }
    __syncthreads();
    if (ks == 0) {
        #pragma unroll
        for (int s2 = 0; s2 < KS - 1; s2++) {
            const float* p = &part[(s2 * RPB + r - rb * RPB) * 5];
            Sall += p[0]; ox += p[1]; oy += p[2]; oz += p[3]; ow += p[4];
        }
        float Sm = Sall - nmask_s;
        float inv = 1.f / (Sm + 1e-13f * Sall);
        float4 o = {ox * inv, oy * inv, oz * inv, ow * inv};
        *(float4*)(o32 + (size_t)(b * T + r) * ATTD + h * 4) = o;
    }
}

// ---------------- mix + L2 normalize: one wave per token ----------------
__global__ __launch_bounds__(256) void mixnorm_kernel(const float* __restrict__ x, const float* __restrict__ xc,
                                                      const float* __restrict__ mask, const float* __restrict__ mixer,
                                                      float* __restrict__ out) {
    int wid = (blockIdx.x * 256 + threadIdx.x) >> 6;
    int lane = threadIdx.x & 63;
    float mixv = mixer[0];
    float mval = mask[wid];
    const float* xr = x + (size_t)wid * EMB;
    const float* xcr = xc + (size_t)wid * EMB;
    float v[5];
    float s2 = 0.f;
    #pragma unroll
    for (int r = 0; r < 5; r++) {
        int idx = lane + r * 64;
        float val = 0.f;
        if (idx < EMB) val = (mixv * xr[idx] + (1.f - mixv) * xcr[idx]) * mval;
        v[r] = val;
        s2 += val * val;
    }
    s2 = wave_sum(s2);
    float inv = 1.f / (sqrtf(s2) + 1e-13f);
    float* o = out + (size_t)wid * EMB;
    #pragma unroll
    for (int r = 0; r < 5; r++) {
        int idx = lane + r * 64;
        if (idx < EMB) o[idx] = v[r] * inv;
    }
}

// ---------------- batched NT GEMM: cos[b] = qn[b] (64x300) @ dn[b]^T (300x512) ----------------
__global__ __launch_bounds__(256) void gemm_nt_cos(const float* __restrict__ Qn, const float* __restrict__ Dn,
                                                   float* __restrict__ Cos) {
    int b = blockIdx.y;
    int n0 = blockIdx.x * 64;
    const float* A = Qn + (size_t)b * LQ * EMB;
    const float* Bm = Dn + (size_t)b * LD * EMB;
    __shared__ __align__(16) float As[16][68];
    __shared__ __align__(16) float Bs[16][68];
    const int tid = threadIdx.x;
    const int tr = tid >> 4, tc = tid & 15;
    float acc[4][4] = {};
    for (int k0 = 0; k0 < EMB; k0 += 16) {
        #pragma unroll
        for (int i = 0; i < 4; i++) {
            int idx = tid + i * 256;
            int r = idx >> 4, cl = idx & 15;
            int kk = k0 + cl;
            As[cl][r] = (kk < EMB) ? A[(size_t)r * EMB + kk] : 0.f;
            Bs[cl][r] = (kk < EMB) ? Bm[(size_t)(n0 + r) * EMB + kk] : 0.f;
        }
        __syncthreads();
        #pragma unroll
        for (int kk = 0; kk < 16; kk++) {
            float4 a4 = *(const float4*)&As[kk][tr * 4];
            float4 b4 = *(const float4*)&Bs[kk][tc * 4];
            float av[4] = {a4.x, a4.y, a4.z, a4.w};
            float bv[4] = {b4.x, b4.y, b4.z, b4.w};
            #pragma unroll
            for (int i = 0; i < 4; i++)
                #pragma unroll
                for (int j = 0; j < 4; j++) acc[i][j] += av[i] * bv[j];
        }
        __syncthreads();
    }
    #pragma unroll
    for (int i = 0; i < 4; i++) {
        int row = tr * 4 + i;
        #pragma unroll
        for (int j = 0; j < 4; j++) {
            int col = n0 + tc * 4 + j;
            Cos[(size_t)b * LQ * LD + (size_t)row * LD + col] = acc[i][j];
        }
    }
}

// ---------------- kernel pooling: one wave per (b, qi); 21 RBF kernels ----------------
__global__ __launch_bounds__(256) void pool_kernel(const float* __restrict__ Cos, const float* __restrict__ mask_q,
                                                   const float* __restrict__ mask_d, const float* __restrict__ nn_scaler,
                                                   float* __restrict__ lp) {
    int wid = (blockIdx.x * 256 + threadIdx.x) >> 6;
    int lane = threadIdx.x & 63;
    int b = wid >> 6, qi = wid & 63;
    const float* crow = Cos + ((size_t)b * LQ + qi) * LD;
    const float* md = mask_d + b * LD;
    float acc[NK];
    #pragma unroll
    for (int k = 0; k < NK; k++) acc[k] = 0.f;
    #pragma unroll
    for (int r = 0; r < LD / 64; r++) {
        int dj = r * 64 + lane;
        float m = md[dj];
        if (m != 0.f) {
            float cv = crow[dj];
            #pragma unroll
            for (int k = 0; k < NK; k++) {
                float mu = (k == 0) ? 1.0f : (0.95f - 0.1f * (k - 1));
                float neg_inv = (k == 0) ? -500000.0f : -50.0f;  // -1/(2*sigma^2)
                float d = cv - mu;
                acc[k] += expf(d * d * neg_inv);
            }
        }
    }
    float mq = mask_q[b * LQ + qi];
    float ns = nn_scaler[0];
    #pragma unroll
    for (int k = 0; k < NK; k++) {
        float s = wave_sum(acc[k]);
        if (lane == 0) lp[((size_t)b * LQ + qi) * NK + k] = log2f(fmaxf(s, 1e-10f)) * ns * mq;
    }
}

// ---------------- final: out[b] = sum_k dense_w[k] * sum_qi lp[b,qi,k] ----------------
__global__ void final_kernel(const float* __restrict__ lp, const float* __restrict__ dense_w,
                             float* __restrict__ out) {
    int b = blockIdx.x;
    int t = threadIdx.x;  // 64 threads
    float s = 0.f;
    if (t < NK) {
        for (int qi = 0; qi < LQ; qi++) s += lp[((size_t)b * LQ + qi) * NK + t];
        s *= dense_w[t];
    }
    s = wave_sum(s);
    if (t == 0) out[b] = s;
}

// ---------------- host-side encoder driver ----------------
static void run_encoder(const float* x_in, float* x_out, int T, const float* mask,
                        const float* ff_w1, const float* ff_b1, const float* ff_w2, const float* ff_b2,
                        const float* ln1_g, const float* ln1_b, const float* att_w, const float* att_b,
                        const float* out_w, const float* out_b, const float* ln2_g, const float* ln2_b,
                        float* t1, float* t2, float* hb, float* cb, float* o32, hipStream_t stream) {
    int M = BATCH * T;
    const float* xcur = x_in;
    for (int l = 0; l < 2; l++) {
        gemm_nn<1><<<dim3(2, M / 64), 256, 0, stream>>>(xcur, ff_w1 + l * EMB * FFH, ff_b1 + l * FFH,
                                                        nullptr, t1, M, FFH, EMB);
        gemm_nn<2><<<dim3(5, M / 64), 256, 0, stream>>>(t1, ff_w2 + l * FFH * EMB, ff_b2 + l * EMB,
                                                        xcur, t2, M, EMB, FFH);
        ln_kernel<<<M / 4, 256, 0, stream>>>(t2, ln1_g + l * EMB, ln1_b + l * EMB, hb, M);
        gemm_nn<0><<<dim3(2, M / 64), 256, 0, stream>>>(hb, att_w + l * EMB * 96, att_b + l * 96,
                                                        nullptr, cb, M, 96, EMB);
        if (T == LD)
            attn_fused<LD, 128, 4><<<BATCH * NH * (LD / 128), 512, 0, stream>>>(cb, mask, o32);
        else
            attn_fused<LQ, 64, 8><<<BATCH * NH, 512, 0, stream>>>(cb, mask, o32);
        gemm_nn<2><<<dim3(5, M / 64), 256, 0, stream>>>(o32, out_w + l * ATTD * EMB, out_b + l * EMB,
                                                        hb, t2, M, EMB, ATTD);
        ln_kernel<<<M / 4, 256, 0, stream>>>(t2, ln2_g + l * EMB, ln2_b + l * EMB, x_out, M);
        xcur = x_out;
    }
}

extern "C" void kernel_launch(void* const* d_in, const int* in_sizes, int n_in,
                              void* d_out, int out_size, void* d_ws, size_t ws_size,
                              hipStream_t stream) {
    (void)in_sizes; (void)n_in; (void)out_size; (void)ws_size;
    const float* q_embed  = (const float*)d_in[0];
    const float* d_embed  = (const float*)d_in[1];
    const float* mask_q   = (const float*)d_in[2];
    const float* mask_d   = (const float*)d_in[3];
    const float* mixer    = (const float*)d_in[4];
    const float* nn_scaler= (const float*)d_in[5];
    const float* ff_w1    = (const float*)d_in[6];
    const float* ff_b1    = (const float*)d_in[7];
    const float* ff_w2    = (const float*)d_in[8];
    const float* ff_b2    = (const float*)d_in[9];
    const float* ln1_g    = (const float*)d_in[10];
    const float* ln1_b    = (const float*)d_in[11];
    const float* att_w    = (const float*)d_in[12];
    const float* att_b    = (const float*)d_in[13];
    const float* out_w    = (const float*)d_in[14];
    const float* out_b    = (const float*)d_in[15];
    const float* ln2_g    = (const float*)d_in[16];
    const float* ln2_b    = (const float*)d_in[17];
    const float* dense_w  = (const float*)d_in[18];
    float* out = (float*)d_out;

    // workspace layout (floats)
    float* ws = (float*)d_ws;
    float* xq  = ws;                       // 32*64*300   = 614400
    float* xd  = xq + 614400;              // 32*512*300  = 4915200
    float* qc  = xd + 4915200;             // 614400
    float* dc  = qc + 614400;              // 4915200
    float* t1  = dc + 4915200;             // 32*512*100  = 1638400
    float* t2  = t1 + 1638400;             // 4915200
    float* hb  = t2 + 4915200;             // 4915200
    float* cb  = hb + 4915200;             // 32*512*96   = 1572864
    float* o32 = cb + 1572864;             // 32*512*32   = 524288
    // reused after encoders complete:
    float* qn   = t1;                      // 614400
    float* dn   = hb;                      // 4915200
    float* cosb = t2;                      // 32*64*512   = 1048576
    float* lp   = o32;                     // 32*64*21    = 43008

    // 1. masked inputs
    maskmul_kernel<<<(614400 + 255) / 256, 256, 0, stream>>>(q_embed, mask_q, xq, 614400);
    maskmul_kernel<<<(4915200 + 255) / 256, 256, 0, stream>>>(d_embed, mask_d, xd, 4915200);

    // 2. encoders
    run_encoder(xq, qc, LQ, mask_q, ff_w1, ff_b1, ff_w2, ff_b2, ln1_g, ln1_b,
                att_w, att_b, out_w, out_b, ln2_g, ln2_b, t1, t2, hb, cb, o32, stream);
    run_encoder(xd, dc, LD, mask_d, ff_w1, ff_b1, ff_w2, ff_b2, ln1_g, ln1_b,
                att_w, att_b, out_w, out_b, ln2_g, ln2_b, t1, t2, hb, cb, o32, stream);

    // 3. mix + normalize
    mixnorm_kernel<<<(BATCH * LQ) / 4, 256, 0, stream>>>(xq, qc, mask_q, mixer, qn);
    mixnorm_kernel<<<(BATCH * LD) / 4, 256, 0, stream>>>(xd, dc, mask_d, mixer, dn);

    // 4. cosine matrix
    gemm_nt_cos<<<dim3(LD / 64, BATCH), 256, 0, stream>>>(qn, dn, cosb);

    // 5. kernel pooling
    pool_kernel<<<(BATCH * LQ) / 4, 256, 0, stream>>>(cosb, mask_q, mask_d, nn_scaler, lp);

    // 6. final projection
    final_kernel<<<BATCH, 64, 0, stream>>>(lp, dense_w, out);
}

// Round 4
// 444.175 us; speedup vs baseline: 2.8534x; 1.6562x over previous
//
#include <hip/hip_runtime.h>
#include <hip/hip_bf16.h>

// Problem constants
#define BATCH 32
#define LQ 64
#define LD 512
#define EMB 300
#define FFH 100
#define ATTD 32
#define NH 8
#define NK 21
#define MQ (BATCH * LQ)          // 2048 query tokens
#define MD (BATCH * LD)          // 16384 doc tokens
#define MALL (MQ + MD)           // 18432 merged tokens

__device__ __forceinline__ float wave_sum(float v) {
    #pragma unroll
    for (int off = 32; off > 0; off >>= 1) v += __shfl_xor(v, off);
    return v;
}

// ---------------- elementwise: x = emb * mask(token) ----------------
__global__ void maskmul_kernel(const float* __restrict__ emb, const float* __restrict__ mask,
                               float* __restrict__ out, int n) {
    int i = blockIdx.x * blockDim.x + threadIdx.x;
    if (i < n) out[i] = emb[i] * mask[i / EMB];
}

// ---------------- mask concat: [mask_q | mask_d] -> maskall[18432] ----------------
__global__ void maskcat_kernel(const float* __restrict__ mq, const float* __restrict__ md,
                               float* __restrict__ out) {
    int i = blockIdx.x * blockDim.x + threadIdx.x;
    if (i < MALL) out[i] = (i < MQ) ? mq[i] : md[i - MQ];
}

// ---------------- generic tiled GEMM: C[M,N] = A[M,K] @ B[K,N] + bias (+relu / +residual) ----
// EPI: 0 = bias, 1 = bias+relu, 2 = bias+residual. float4-vectorized staging.
template <int EPI>
__global__ __launch_bounds__(256) void gemm_nn(const float* __restrict__ A, const float* __restrict__ Bw,
                                               const float* __restrict__ bias, const float* __restrict__ R,
                                               float* __restrict__ C, int M, int N, int K) {
    __shared__ __align__(16) float As[16][68];   // [k][m], padded
    __shared__ __align__(16) float Bs[16][64];   // [k][n]
    const int tid = threadIdx.x;
    const int m0 = blockIdx.y * 64, n0 = blockIdx.x * 64;
    const int tr = tid >> 4, tc = tid & 15;
    float acc[4][4] = {};

    for (int k0 = 0; k0 < K; k0 += 16) {
        // A stage: one float4 per thread (64 rows x 16 k), store transposed
        {
            int r = tid >> 2;
            int k4 = (tid & 3) * 4;
            int kk = k0 + k4;
            const float* arow = A + (size_t)(m0 + r) * K;
            float4 av;
            if (kk + 3 < K) {
                av = *(const float4*)(arow + kk);
            } else {
                av.x = (kk     < K) ? arow[kk]     : 0.f;
                av.y = (kk + 1 < K) ? arow[kk + 1] : 0.f;
                av.z = (kk + 2 < K) ? arow[kk + 2] : 0.f;
                av.w = (kk + 3 < K) ? arow[kk + 3] : 0.f;
            }
            As[k4 + 0][r] = av.x;
            As[k4 + 1][r] = av.y;
            As[k4 + 2][r] = av.z;
            As[k4 + 3][r] = av.w;
        }
        // B stage: one float4 per thread (16 k x 64 n)
        {
            int r = tid >> 4;
            int c4 = (tid & 15) * 4;
            int kk = k0 + r;
            int n = n0 + c4;
            float4 bv = {0.f, 0.f, 0.f, 0.f};
            if (kk < K) {
                const float* brow = Bw + (size_t)kk * N;
                if (n + 3 < N) {
                    bv = *(const float4*)(brow + n);
                } else {
                    if (n     < N) bv.x = brow[n];
                    if (n + 1 < N) bv.y = brow[n + 1];
                    if (n + 2 < N) bv.z = brow[n + 2];
                    if (n + 3 < N) bv.w = brow[n + 3];
                }
            }
            *(float4*)&Bs[r][c4] = bv;
        }
        __syncthreads();
        #pragma unroll
        for (int kk = 0; kk < 16; kk++) {
            float4 a4 = *(const float4*)&As[kk][tr * 4];
            float4 b4 = *(const float4*)&Bs[kk][tc * 4];
            float av[4] = {a4.x, a4.y, a4.z, a4.w};
            float bv[4] = {b4.x, b4.y, b4.z, b4.w};
            #pragma unroll
            for (int i = 0; i < 4; i++)
                #pragma unroll
                for (int j = 0; j < 4; j++) acc[i][j] += av[i] * bv[j];
        }
        __syncthreads();
    }
    #pragma unroll
    for (int i = 0; i < 4; i++) {
        int row = m0 + tr * 4 + i;
        #pragma unroll
        for (int j = 0; j < 4; j++) {
            int col = n0 + tc * 4 + j;
            if (col < N) {
                float v = acc[i][j] + bias[col];
                if (EPI == 1) v = fmaxf(v, 0.f);
                if (EPI == 2) v += R[(size_t)row * N + col];
                C[(size_t)row * N + col] = v;
            }
        }
    }
}

// ---------------- LayerNorm (ddof=1, eps added to std), one wave per token (300 elems) ------
__global__ __launch_bounds__(256) void ln_kernel(const float* __restrict__ X, const float* __restrict__ g,
                                                 const float* __restrict__ bta, float* __restrict__ Y, int M) {
    int wid = (blockIdx.x * 256 + threadIdx.x) >> 6;
    int lane = threadIdx.x & 63;
    if (wid >= M) return;
    const float* x = X + (size_t)wid * EMB;
    float v[5];
    float s = 0.f;
    #pragma unroll
    for (int r = 0; r < 5; r++) {
        int idx = lane + r * 64;
        float val = (idx < EMB) ? x[idx] : 0.f;
        v[r] = val;
        s += val;
    }
    s = wave_sum(s);
    float mean = s * (1.f / EMB);
    float s2 = 0.f;
    #pragma unroll
    for (int r = 0; r < 5; r++) {
        int idx = lane + r * 64;
        if (idx < EMB) { float d = v[r] - mean; s2 += d * d; }
    }
    s2 = wave_sum(s2);
    float stdv = sqrtf(s2 * (1.f / (EMB - 1)));
    float inv = 1.f / (stdv + 1e-6f);
    float* y = Y + (size_t)wid * EMB;
    #pragma unroll
    for (int r = 0; r < 5; r++) {
        int idx = lane + r * 64;
        if (idx < EMB) y[idx] = g[idx] * (v[r] - mean) * inv + bta[idx];
    }
}

// ---------------- attention: single-pass (no max), premasked K/V in LDS, k-split ---------
// c layout: [tokens, 96]  (q | k | v, each 32 = 8 heads * 4)
template <int T, int RPB, int KS>
__global__ __launch_bounds__(512) void attn_fused(const float* __restrict__ c,
                                                  const float* __restrict__ mask,
                                                  float* __restrict__ o32) {
    constexpr int BLK = RPB * KS;
    constexpr int NRB = T / RPB;
    __shared__ float4 Ks[T];
    __shared__ float4 Vs[T];
    __shared__ float part[RPB * 5 * (KS - 1)];
    __shared__ float nmask_s;
    const int bh = blockIdx.x / NRB;
    const int rb = blockIdx.x % NRB;
    const int b = bh / NH, h = bh % NH;
    const int tid = threadIdx.x;
    const float* base = c + (size_t)b * T * 96;

    if (tid == 0) nmask_s = 0.f;
    __syncthreads();
    float lnm = 0.f;
    for (int j = tid; j < T; j += BLK) {
        float m = mask[b * T + j];
        float4 kv = *(const float4*)(base + (size_t)j * 96 + ATTD + h * 4);
        float4 vv = *(const float4*)(base + (size_t)j * 96 + 2 * ATTD + h * 4);
        kv.x *= m; kv.y *= m; kv.z *= m; kv.w *= m;
        vv.x *= m; vv.y *= m; vv.z *= m; vv.w *= m;
        Ks[j] = kv;
        Vs[j] = vv;
        lnm += 1.f - m;
    }
    lnm = wave_sum(lnm);
    if ((tid & 63) == 0 && lnm != 0.f) atomicAdd(&nmask_s, lnm);
    __syncthreads();

    const int r = rb * RPB + (tid % RPB);
    const int ks = tid / RPB;
    const float inv_scale = 0.16439898730535729f;  // 1/sqrt(37)
    float4 qv = *(const float4*)(base + (size_t)r * 96 + h * 4);
    qv.x *= inv_scale; qv.y *= inv_scale; qv.z *= inv_scale; qv.w *= inv_scale;

    float Sall = 0.f, ox = 0.f, oy = 0.f, oz = 0.f, ow = 0.f;
    constexpr int KC = T / KS;
    const int k0 = ks * KC;
    #pragma unroll 4
    for (int k = k0; k < k0 + KC; k++) {
        float4 kv = Ks[k];
        float4 vv = Vs[k];
        float s = fmaf(qv.x, kv.x, fmaf(qv.y, kv.y, fmaf(qv.z, kv.z, qv.w * kv.w)));
        float e = __expf(s);
        Sall += e;
        ox = fmaf(e, vv.x, ox);
        oy = fmaf(e, vv.y, oy);
        oz = fmaf(e, vv.z, oz);
        ow = fmaf(e, vv.w, ow);
    }
    if (ks > 0) {
        float* p = &part[((ks - 1) * RPB + (tid % RPB)) * 5];
        p[0] = Sall; p[1] = ox; p[2] = oy; p[3] = oz; p[4] = ow;
    }
    __syncthreads();
    if (ks == 0) {
        #pragma unroll
        for (int s2 = 0; s2 < KS - 1; s2++) {
            const float* p = &part[(s2 * RPB + r - rb * RPB) * 5];
            Sall += p[0]; ox += p[1]; oy += p[2]; oz += p[3]; ow += p[4];
        }
        float Sm = Sall - nmask_s;
        float inv = 1.f / (Sm + 1e-13f * Sall);
        float4 o = {ox * inv, oy * inv, oz * inv, ow * inv};
        *(float4*)(o32 + (size_t)(b * T + r) * ATTD + h * 4) = o;
    }
}

// ---------------- mix + L2 normalize: one wave per token (merged stream) ----------------
__global__ __launch_bounds__(256) void mixnorm_kernel(const float* __restrict__ x, const float* __restrict__ xc,
                                                      const float* __restrict__ mask, const float* __restrict__ mixer,
                                                      float* __restrict__ out) {
    int wid = (blockIdx.x * 256 + threadIdx.x) >> 6;
    int lane = threadIdx.x & 63;
    float mixv = mixer[0];
    float mval = mask[wid];
    const float* xr = x + (size_t)wid * EMB;
    const float* xcr = xc + (size_t)wid * EMB;
    float v[5];
    float s2 = 0.f;
    #pragma unroll
    for (int r = 0; r < 5; r++) {
        int idx = lane + r * 64;
        float val = 0.f;
        if (idx < EMB) val = (mixv * xr[idx] + (1.f - mixv) * xcr[idx]) * mval;
        v[r] = val;
        s2 += val * val;
    }
    s2 = wave_sum(s2);
    float inv = 1.f / (sqrtf(s2) + 1e-13f);
    float* o = out + (size_t)wid * EMB;
    #pragma unroll
    for (int r = 0; r < 5; r++) {
        int idx = lane + r * 64;
        if (idx < EMB) o[idx] = v[r] * inv;
    }
}

// ---------------- batched NT GEMM: cos[b] = qn[b] (64x300) @ dn[b]^T (300x512) ----------------
__global__ __launch_bounds__(256) void gemm_nt_cos(const float* __restrict__ Qn, const float* __restrict__ Dn,
                                                   float* __restrict__ Cos) {
    int b = blockIdx.y;
    int n0 = blockIdx.x * 64;
    const float* A = Qn + (size_t)b * LQ * EMB;
    const float* Bm = Dn + (size_t)b * LD * EMB;
    __shared__ __align__(16) float As[16][68];
    __shared__ __align__(16) float Bs[16][68];
    const int tid = threadIdx.x;
    const int tr = tid >> 4, tc = tid & 15;
    float acc[4][4] = {};
    for (int k0 = 0; k0 < EMB; k0 += 16) {
        #pragma unroll
        for (int i = 0; i < 4; i++) {
            int idx = tid + i * 256;
            int r = idx >> 4, cl = idx & 15;
            int kk = k0 + cl;
            As[cl][r] = (kk < EMB) ? A[(size_t)r * EMB + kk] : 0.f;
            Bs[cl][r] = (kk < EMB) ? Bm[(size_t)(n0 + r) * EMB + kk] : 0.f;
        }
        __syncthreads();
        #pragma unroll
        for (int kk = 0; kk < 16; kk++) {
            float4 a4 = *(const float4*)&As[kk][tr * 4];
            float4 b4 = *(const float4*)&Bs[kk][tc * 4];
            float av[4] = {a4.x, a4.y, a4.z, a4.w};
            float bv[4] = {b4.x, b4.y, b4.z, b4.w};
            #pragma unroll
            for (int i = 0; i < 4; i++)
                #pragma unroll
                for (int j = 0; j < 4; j++) acc[i][j] += av[i] * bv[j];
        }
        __syncthreads();
    }
    #pragma unroll
    for (int i = 0; i < 4; i++) {
        int row = tr * 4 + i;
        #pragma unroll
        for (int j = 0; j < 4; j++) {
            int col = n0 + tc * 4 + j;
            Cos[(size_t)b * LQ * LD + (size_t)row * LD + col] = acc[i][j];
        }
    }
}

// ---------------- kernel pooling: one wave per (b, qi); 21 RBF kernels ----------------
__global__ __launch_bounds__(256) void pool_kernel(const float* __restrict__ Cos, const float* __restrict__ mask_q,
                                                   const float* __restrict__ mask_d, const float* __restrict__ nn_scaler,
                                                   float* __restrict__ lp) {
    int wid = (blockIdx.x * 256 + threadIdx.x) >> 6;
    int lane = threadIdx.x & 63;
    int b = wid >> 6, qi = wid & 63;
    const float* crow = Cos + ((size_t)b * LQ + qi) * LD;
    const float* md = mask_d + b * LD;
    float acc[NK];
    #pragma unroll
    for (int k = 0; k < NK; k++) acc[k] = 0.f;
    #pragma unroll
    for (int r = 0; r < LD / 64; r++) {
        int dj = r * 64 + lane;
        float m = md[dj];
        if (m != 0.f) {
            float cv = crow[dj];
            #pragma unroll
            for (int k = 0; k < NK; k++) {
                float mu = (k == 0) ? 1.0f : (0.95f - 0.1f * (k - 1));
                float neg_inv = (k == 0) ? -500000.0f : -50.0f;
                float d = cv - mu;
                acc[k] += expf(d * d * neg_inv);
            }
        }
    }
    float mq = mask_q[b * LQ + qi];
    float ns = nn_scaler[0];
    #pragma unroll
    for (int k = 0; k < NK; k++) {
        float s = wave_sum(acc[k]);
        if (lane == 0) lp[((size_t)b * LQ + qi) * NK + k] = log2f(fmaxf(s, 1e-10f)) * ns * mq;
    }
}

// ---------------- final: out[b] = sum_k dense_w[k] * sum_qi lp[b,qi,k] ----------------
__global__ void final_kernel(const float* __restrict__ lp, const float* __restrict__ dense_w,
                             float* __restrict__ out) {
    int b = blockIdx.x;
    int t = threadIdx.x;  // 64 threads
    float s = 0.f;
    if (t < NK) {
        for (int qi = 0; qi < LQ; qi++) s += lp[((size_t)b * LQ + qi) * NK + t];
        s *= dense_w[t];
    }
    s = wave_sum(s);
    if (t == 0) out[b] = s;
}

extern "C" void kernel_launch(void* const* d_in, const int* in_sizes, int n_in,
                              void* d_out, int out_size, void* d_ws, size_t ws_size,
                              hipStream_t stream) {
    (void)in_sizes; (void)n_in; (void)out_size; (void)ws_size;
    const float* q_embed  = (const float*)d_in[0];
    const float* d_embed  = (const float*)d_in[1];
    const float* mask_q   = (const float*)d_in[2];
    const float* mask_d   = (const float*)d_in[3];
    const float* mixer    = (const float*)d_in[4];
    const float* nn_scaler= (const float*)d_in[5];
    const float* ff_w1    = (const float*)d_in[6];
    const float* ff_b1    = (const float*)d_in[7];
    const float* ff_w2    = (const float*)d_in[8];
    const float* ff_b2    = (const float*)d_in[9];
    const float* ln1_g    = (const float*)d_in[10];
    const float* ln1_b    = (const float*)d_in[11];
    const float* att_w    = (const float*)d_in[12];
    const float* att_b    = (const float*)d_in[13];
    const float* out_w    = (const float*)d_in[14];
    const float* out_b    = (const float*)d_in[15];
    const float* ln2_g    = (const float*)d_in[16];
    const float* ln2_b    = (const float*)d_in[17];
    const float* dense_w  = (const float*)d_in[18];
    float* out = (float*)d_out;

    // workspace layout (floats) — merged token stream: [q tokens (2048) | d tokens (16384)]
    float* ws   = (float*)d_ws;
    float* x    = ws;                      // MALL*300 = 5,529,600 (masked embeddings, persists)
    float* xc   = x   + (size_t)MALL * EMB; // 5,529,600 (encoder output / layer chain)
    float* t2   = xc  + (size_t)MALL * EMB; // 5,529,600
    float* hb   = t2  + (size_t)MALL * EMB; // 5,529,600
    float* t1cb = hb  + (size_t)MALL * EMB; // max(MALL*100, MALL*96) = 1,843,200
    float* o32  = t1cb + (size_t)MALL * FFH; // MALL*32 = 589,824
    float* mall = o32 + (size_t)MALL * ATTD; // 18,432
    // post-encoder aliases:
    float* qdn  = t2;                      // mixed+normalized tokens
    float* cosb = hb;                      // 32*64*512 = 1,048,576
    float* lp   = o32;                     // 32*64*21

    // 1. masked inputs (q segment then d segment) + mask concat
    maskmul_kernel<<<(MQ * EMB + 255) / 256, 256, 0, stream>>>(q_embed, mask_q, x, MQ * EMB);
    maskmul_kernel<<<(MD * EMB + 255) / 256, 256, 0, stream>>>(d_embed, mask_d, x + (size_t)MQ * EMB, MD * EMB);
    maskcat_kernel<<<(MALL + 255) / 256, 256, 0, stream>>>(mask_q, mask_d, mall);

    // 2. merged encoder (q+d share weights; attention splits by segment)
    const float* xcur = x;
    for (int l = 0; l < 2; l++) {
        gemm_nn<1><<<dim3(2, MALL / 64), 256, 0, stream>>>(xcur, ff_w1 + l * EMB * FFH, ff_b1 + l * FFH,
                                                           nullptr, t1cb, MALL, FFH, EMB);
        gemm_nn<2><<<dim3(5, MALL / 64), 256, 0, stream>>>(t1cb, ff_w2 + l * FFH * EMB, ff_b2 + l * EMB,
                                                           xcur, t2, MALL, EMB, FFH);
        ln_kernel<<<MALL / 4, 256, 0, stream>>>(t2, ln1_g + l * EMB, ln1_b + l * EMB, hb, MALL);
        gemm_nn<0><<<dim3(2, MALL / 64), 256, 0, stream>>>(hb, att_w + l * EMB * 96, att_b + l * 96,
                                                           nullptr, t1cb, MALL, 96, EMB);
        attn_fused<LQ, 64, 8><<<BATCH * NH, 512, 0, stream>>>(t1cb, mask_q, o32);
        attn_fused<LD, 128, 4><<<BATCH * NH * (LD / 128), 512, 0, stream>>>(
            t1cb + (size_t)MQ * 96, mask_d, o32 + (size_t)MQ * ATTD);
        gemm_nn<2><<<dim3(5, MALL / 64), 256, 0, stream>>>(o32, out_w + l * ATTD * EMB, out_b + l * EMB,
                                                           hb, t2, MALL, EMB, ATTD);
        ln_kernel<<<MALL / 4, 256, 0, stream>>>(t2, ln2_g + l * EMB, ln2_b + l * EMB, xc, MALL);
        xcur = xc;
    }

    // 3. mix + normalize (merged)
    mixnorm_kernel<<<MALL / 4, 256, 0, stream>>>(x, xc, mall, mixer, qdn);

    // 4. cosine matrix (q segment vs d segment of qdn)
    gemm_nt_cos<<<dim3(LD / 64, BATCH), 256, 0, stream>>>(qdn, qdn + (size_t)MQ * EMB, cosb);

    // 5. kernel pooling
    pool_kernel<<<(BATCH * LQ) / 4, 256, 0, stream>>>(cosb, mask_q, mask_d, nn_scaler, lp);

    // 6. final projection
    final_kernel<<<BATCH, 64, 0, stream>>>(lp, dense_w, out);
}